// Round 19
// baseline (169.708 us; speedup 1.0000x reference)
//
#include <hip/hip_runtime.h>

typedef unsigned short u16;
typedef __attribute__((ext_vector_type(8))) short bf16x8;
typedef __attribute__((ext_vector_type(16))) float f32x16;
typedef __attribute__((ext_vector_type(2))) int i32x2;

#define MFMA32(A, B, C) __builtin_amdgcn_mfma_f32_32x32x16_bf16((A), (B), (C), 0, 0, 0)

// constants
#define BB 4
#define CC 256
#define HW 4096
#define NH 4
#define HD 64

// 0.125 (d^-0.5) * log2(e): softmax done in exp2 domain
#define QSCALE 0.18033688f

__device__ __forceinline__ u16 f2bf(float f) {
  unsigned int u = __builtin_bit_cast(unsigned int, f);
  u += 0x7fffu + ((u >> 16) & 1u);   // RNE
  return (u16)(u >> 16);
}

__device__ __forceinline__ unsigned cvtpk(float a, float b) {
  unsigned r;
  asm("v_cvt_pk_bf16_f32 %0, %1, %2" : "=v"(r) : "v"(a), "v"(b));
  return r;
}

// D-layout (32x32) octet -> fragment pack: returns lane chunk of 8 bf16 =
// rows oct*16 + hi*8 + 0..7 of this lane's column. scl may be per-lane.
__device__ __forceinline__ uint4 pack_oct(const f32x16& a, int oct, float scl) {
  const int b8 = oct * 8;
  unsigned A0 = cvtpk(a[b8 + 0] * scl, a[b8 + 1] * scl);
  unsigned A1 = cvtpk(a[b8 + 2] * scl, a[b8 + 3] * scl);
  unsigned B0 = cvtpk(a[b8 + 4] * scl, a[b8 + 5] * scl);
  unsigned B1 = cvtpk(a[b8 + 6] * scl, a[b8 + 7] * scl);
  i32x2 r0 = __builtin_amdgcn_permlane32_swap((int)A0, (int)B0, false, false);
  i32x2 r1 = __builtin_amdgcn_permlane32_swap((int)A1, (int)B1, false, false);
  union { unsigned w[4]; uint4 v; } u;
  u.w[0] = (unsigned)r0[0]; u.w[1] = (unsigned)r1[0];
  u.w[2] = (unsigned)r0[1]; u.w[3] = (unsigned)r1[1];
  return u.v;
}

// ---------------- Kernel 0: weights -> FRAGMENT-MAJOR bf16 (once) ----------------
__global__ __launch_bounds__(256) void w2bf_kernel(const float* __restrict__ qw,
                                                   const float* __restrict__ pw,
                                                   u16* __restrict__ w_f) {
  int wv = (blockIdx.x * 256 + threadIdx.x) >> 6;   // 0..511 wave-task
  int lane = threadIdx.x & 63;
  int row = (wv >> 4) * 32 + (lane & 31);
  int c0 = (wv & 15) * 16 + (lane >> 5) * 8;
  const float* src = (row < 768) ? (qw + (size_t)row * 256 + c0)
                                 : (pw + (size_t)(row - 768) * 256 + c0);
  float4 a = *(const float4*)src;
  float4 b = *(const float4*)(src + 4);
  union { u16 u[8]; uint4 v; } pk;
  pk.u[0] = f2bf(a.x); pk.u[1] = f2bf(a.y); pk.u[2] = f2bf(a.z); pk.u[3] = f2bf(a.w);
  pk.u[4] = f2bf(b.x); pk.u[5] = f2bf(b.y); pk.u[6] = f2bf(b.z); pk.u[7] = f2bf(b.w);
  *(uint4*)(w_f + ((size_t)wv * 64 + lane) * 8) = pk.v;
}

// ---------------- Kernel 1a: GroupNorm partial sums (256 blocks) ----------------
__global__ __launch_bounds__(256) void gn_partial_kernel(const float* __restrict__ x,
                                                         float* __restrict__ partial) {
  const float4* p = (const float4*)(x + (size_t)blockIdx.x * 16384);
  float s = 0.f, ss = 0.f;
  for (int i = threadIdx.x; i < 4096; i += 256) {
    float4 v = p[i];
    s += (v.x + v.y) + (v.z + v.w);
    ss += (v.x * v.x + v.y * v.y) + (v.z * v.z + v.w * v.w);
  }
#pragma unroll
  for (int msk = 32; msk; msk >>= 1) {
    s += __shfl_xor(s, msk);
    ss += __shfl_xor(ss, msk);
  }
  __shared__ float red[2][4];
  int wave = threadIdx.x >> 6;
  if ((threadIdx.x & 63) == 0) { red[0][wave] = s; red[1][wave] = ss; }
  __syncthreads();
  if (threadIdx.x == 0) {
    partial[blockIdx.x] = red[0][0] + red[0][1] + red[0][2] + red[0][3];
    partial[256 + blockIdx.x] = red[1][0] + red[1][1] + red[1][2] + red[1][3];
  }
}

// ---------------- Kernel 1b: finalize stats (1 block) ----------------
__global__ __launch_bounds__(64) void gn_final_kernel(const float* __restrict__ partial,
                                                      float* __restrict__ stats) {
  int bg = threadIdx.x;
  if (bg < 32) {
    float S = 0.f, SS = 0.f;
#pragma unroll
    for (int sp = 0; sp < 8; ++sp) {
      S += partial[bg * 8 + sp];
      SS += partial[256 + bg * 8 + sp];
    }
    const float invN = 1.0f / 131072.0f;
    float mean = S * invN;
    float var = SS * invN - mean * mean;
    stats[bg] = mean;
    stats[32 + bg] = rsqrtf(var + 1e-5f);
  }
}

// ---------------- Kernel 2: normalize + LDS-transpose -> h_f FRAGMENT-MAJOR ----------------
__global__ __launch_bounds__(256) void norm_t_kernel(const float* __restrict__ x,
                                                     const float* __restrict__ nw,
                                                     const float* __restrict__ nb,
                                                     const float* __restrict__ stats,
                                                     u16* __restrict__ h_f) {
  __shared__ u16 L[256][66];   // [c][s] + pad, 33792 B
  int b = blockIdx.y;
  int s0 = blockIdx.x * 64;
  int lane = threadIdx.x & 63, w = threadIdx.x >> 6;
  int c_off = lane >> 4;             // 0..3
  int s_off = (lane & 15) * 4;       // 0,4,..,60
  const float* xb = x + (size_t)b * CC * HW;
#pragma unroll 4
  for (int cc = 0; cc < 16; ++cc) {
    int c = w * 64 + cc * 4 + c_off;
    int g = c >> 5;
    float mean = stats[b * 8 + g];
    float rstd = stats[32 + b * 8 + g];
    float a = nw[c] * rstd;
    float b2 = nb[c] - mean * a;
    float4 v = *(const float4*)(xb + (size_t)c * HW + s0 + s_off);
    union { u16 u[4]; uint2 q; } pk;
    pk.u[0] = f2bf(v.x * a + b2);
    pk.u[1] = f2bf(v.y * a + b2);
    pk.u[2] = f2bf(v.z * a + b2);
    pk.u[3] = f2bf(v.w * a + b2);
    *(uint2*)&L[c][s_off] = pk.q;
  }
  __syncthreads();
  u16* hb = h_f + (size_t)b * HW * CC;
  int ql = lane & 31, hi = lane >> 5;
  for (int t = w; t < 32; t += 4) {
    int s32t = t >> 4, kc = t & 15;
    int c0 = kc * 16 + hi * 8;
    int s = s32t * 32 + ql;
    union { u16 u[8]; uint4 v; } pk;
#pragma unroll
    for (int j = 0; j < 8; ++j) pk.u[j] = L[c0 + j][s];
    int s32g = (s0 >> 5) + s32t;
    *(uint4*)(hb + ((size_t)(s32g * 16 + kc) * 64 + lane) * 8) = pk.v;
  }
}

// ---------------- Kernel 3: QKV GEMM, h-tile staged in LDS, all 6 o-groups ----------------
// grid (HW/128, B), 256 thr. Phase 1: copy h_f tile [4 s32][16 kc][64 lane][8]
// (64KB, linear fragment layout) to LDS once. Phase 2: loop y=0..5, h from
// LDS (ds_read_b128, lane-contiguous), w from L2 (512KB resident). Cuts h_f
// global traffic 6x (48MB -> 8MB).
__global__ __launch_bounds__(256) void qkv_kernel(const u16* __restrict__ h_f,
                                                  const u16* __restrict__ w_f,
                                                  const float* __restrict__ qb,
                                                  u16* __restrict__ q_f,
                                                  u16* __restrict__ k_f,
                                                  u16* __restrict__ v_f) {
  __shared__ __align__(16) u16 hL[4][16][64 * 8];   // 64KB: [s32][kc][lane*8]
  int b = blockIdx.y;
  int lane = threadIdx.x & 63, wave = threadIdx.x >> 6;
  int ql = lane & 31, hi = lane >> 5;
  int s0 = blockIdx.x * 128;
  int ss32 = s0 >> 5;
  const u16* hb = h_f + (size_t)b * HW * CC;

  // phase 1: stage h tile (each wave copies one s32 row: 16 x 1KB)
  {
    const u16* src = hb + ((size_t)((ss32 + wave) * 16) * 64 + lane) * 8;
#pragma unroll
    for (int kc = 0; kc < 16; ++kc)
      *(uint4*)&hL[wave][kc][lane * 8] = *(const uint4*)(src + (size_t)kc * 512);
  }
  __syncthreads();

  int sw = wave >> 1;                 // 0..1: s-subtile (2 x s32)
  int ow = wave & 1;                  // 0..1: o-subtile within y
#pragma unroll 1
  for (int y = 0; y < 6; ++y) {
    int o0w = y * 128 + ow * 64;      // 0..767
    bool isV = (y >= 4);
    f32x16 acc[2][2];
    if (!isV) {
#pragma unroll
      for (int mo = 0; mo < 2; ++mo)
#pragma unroll
        for (int r = 0; r < 16; ++r) {
          int row = (r & 3) + 8 * (r >> 2) + 4 * hi;
          float bv = qb[o0w + mo * 32 + row];
          acc[mo][0][r] = bv;
          acc[mo][1][r] = bv;
        }
    } else {
#pragma unroll
      for (int ns = 0; ns < 2; ++ns) {
        float bv = qb[o0w + ns * 32 + ql];
#pragma unroll
        for (int r = 0; r < 16; ++r) {
          acc[0][ns][r] = bv;
          acc[1][ns][r] = bv;
        }
      }
    }

    int os32 = o0w >> 5;
    const u16* wp = w_f + ((size_t)(os32 * 16) * 64 + lane) * 8;
#pragma unroll 1
    for (int kk = 0; kk < 16; ++kk) {
      bf16x8 wf[2], hf[2];
      wf[0] = *(const bf16x8*)(wp + (size_t)kk * 512);
      wf[1] = *(const bf16x8*)(wp + (size_t)(16 + kk) * 512);
      hf[0] = *(const bf16x8*)&hL[sw * 2 + 0][kk][lane * 8];
      hf[1] = *(const bf16x8*)&hL[sw * 2 + 1][kk][lane * 8];
      if (!isV) {
        acc[0][0] = MFMA32(wf[0], hf[0], acc[0][0]);
        acc[0][1] = MFMA32(wf[0], hf[1], acc[0][1]);
        acc[1][0] = MFMA32(wf[1], hf[0], acc[1][0]);
        acc[1][1] = MFMA32(wf[1], hf[1], acc[1][1]);
      } else {
        acc[0][0] = MFMA32(hf[0], wf[0], acc[0][0]);
        acc[0][1] = MFMA32(hf[0], wf[1], acc[0][1]);
        acc[1][0] = MFMA32(hf[1], wf[0], acc[1][0]);
        acc[1][1] = MFMA32(hf[1], wf[1], acc[1][1]);
      }
    }

    int sbase = ss32 + sw * 2;
    if (!isV) {
      bool isQ = (y < 2);
      float scl = isQ ? QSCALE : 1.0f;
      int headL = (o0w >> 6) - (isQ ? 0 : 4);
      u16* base = (isQ ? q_f : k_f) + (size_t)(b * NH + headL) * HW * HD;
#pragma unroll
      for (int mo = 0; mo < 2; ++mo)
#pragma unroll
        for (int ns = 0; ns < 2; ++ns) {
          int s32 = sbase + ns;
#pragma unroll
          for (int oct = 0; oct < 2; ++oct) {
            int kc = mo * 2 + oct;
            uint4 v = pack_oct(acc[mo][ns], oct, scl);
            *(uint4*)(base + ((size_t)(s32 * 4 + kc) * 64 + lane) * 8) = v;
          }
        }
    } else {
      int headv = (o0w >> 6) - 8;
      u16* base = v_f + (size_t)(b * NH + headv) * HW * HD;
#pragma unroll
      for (int mo = 0; mo < 2; ++mo)
#pragma unroll
        for (int ns = 0; ns < 2; ++ns)
#pragma unroll
          for (int oct = 0; oct < 2; ++oct) {
            int kvb = sbase * 32 + mo * 32 + oct * 16;
            int jb64 = kvb >> 6, kcv = (kvb & 63) >> 4;
            uint4 v = pack_oct(acc[mo][ns], oct, 1.0f);
            *(uint4*)(base + ((size_t)((jb64 * 2 + ns) * 4 + kcv) * 64 + lane) * 8) = v;
          }
    }
  }
}

// ---------------- Kernel 5: flash attention, LDS-free + split-KV x2 (R15 best) ----------------
__global__ __launch_bounds__(512) void attn_kernel(const u16* __restrict__ q_f,
                                                   const u16* __restrict__ k_f,
                                                   const u16* __restrict__ v_f,
                                                   u16* __restrict__ o_f) {
  __shared__ float mbuf[4 * 33 * 64];   // [wsub][of0(16)|of1(16)|l(1)][lane]
  int wgid = blockIdx.x + gridDim.x * blockIdx.y;
  int xcd = wgid & 7;
  int j = wgid >> 3;
  int bh = (xcd << 1) | (j & 1);       // each XCD owns 2 bh -> L2-resident K/V
  int qblk = j >> 1;
  int tid = threadIdx.x;
  int wave = tid >> 6, lane = tid & 63;
  int half = wave >> 2, wsub = wave & 3;
  int ql = lane & 31, hi = lane >> 5;
  int q0w = qblk * 128 + wsub * 32;
  const u16* qfb = q_f + (size_t)bh * HW * HD + lane * 8;
  const u16* kfb = k_f + (size_t)bh * HW * HD + lane * 8;
  const u16* vfb = v_f + (size_t)bh * HW * HD + lane * 8;

  // Q B-fragments from fragment-major layout
  int s32q = q0w >> 5;
  bf16x8 qf[4];
#pragma unroll
  for (int kc = 0; kc < 4; ++kc)
    qf[kc] = *(const bf16x8*)(qfb + (size_t)(s32q * 4 + kc) * 512);

  float l_run = 0.f;
  f32x16 of0 = {}, of1 = {};
  bf16x8 kfr[8], vfr[8];

  // prologue: K(half), V(half) fragments
  {
    const u16* kb = kfb + (size_t)half * 4096;
    const u16* vb = vfb + (size_t)half * 4096;
#pragma unroll
    for (int kc = 0; kc < 4; ++kc) {
      kfr[kc] = *(const bf16x8*)(kb + (size_t)kc * 512);
      kfr[4 + kc] = *(const bf16x8*)(kb + (size_t)(4 + kc) * 512);
      vfr[kc] = *(const bf16x8*)(vb + (size_t)kc * 512);
      vfr[4 + kc] = *(const bf16x8*)(vb + (size_t)(4 + kc) * 512);
    }
  }

#pragma unroll 1
  for (int it = half; it < 64; it += 2) {
    // QK(it): S[kv][q] = K·Q  (scale+log2e folded into q)
    f32x16 s0 = {}, s1 = {};
    __builtin_amdgcn_s_setprio(1);
#pragma unroll
    for (int kc = 0; kc < 4; ++kc) {
      s0 = MFMA32(kfr[kc], qf[kc], s0);
      s1 = MFMA32(kfr[4 + kc], qf[kc], s1);
    }
    __builtin_amdgcn_s_setprio(0);

    // K(it+2) fragment loads (consumed next iteration)
    {
      const u16* kb = kfb + (size_t)(it + 2) * 4096;
#pragma unroll
      for (int kc = 0; kc < 4; ++kc) {
        kfr[kc] = *(const bf16x8*)(kb + (size_t)kc * 512);
        kfr[4 + kc] = *(const bf16x8*)(kb + (size_t)(4 + kc) * 512);
      }
    }

    // P = exp2(S) directly — fixed reference (no max tracking)
#pragma unroll
    for (int i = 0; i < 16; ++i) {
      s0[i] = __builtin_amdgcn_exp2f(s0[i]);
      s1[i] = __builtin_amdgcn_exp2f(s1[i]);
    }

    // pf(it) = P -> bf16 B-fragments via cvt_pk + permlane32_swap
    bf16x8 pf[4];
#pragma unroll
    for (int kc = 0; kc < 4; ++kc) {
      const f32x16 pv = (kc < 2) ? s0 : s1;
      const int b8 = (kc & 1) * 8;
      unsigned A0 = cvtpk(pv[b8 + 0], pv[b8 + 1]);
      unsigned A1 = cvtpk(pv[b8 + 2], pv[b8 + 3]);
      unsigned B0 = cvtpk(pv[b8 + 4], pv[b8 + 5]);
      unsigned B1 = cvtpk(pv[b8 + 6], pv[b8 + 7]);
      i32x2 r0 = __builtin_amdgcn_permlane32_swap((int)A0, (int)B0, false, false);
      i32x2 r1 = __builtin_amdgcn_permlane32_swap((int)A1, (int)B1, false, false);
      union { unsigned w[4]; bf16x8 v8; } u;
      u.w[0] = (unsigned)r0[0]; u.w[1] = (unsigned)r1[0];
      u.w[2] = (unsigned)r0[1]; u.w[3] = (unsigned)r1[1];
      pf[kc] = u.v8;
    }

    // PV(it): O^T[c][q] += V^T · P^T
    __builtin_amdgcn_s_setprio(1);
#pragma unroll
    for (int kc = 0; kc < 4; ++kc) {
      of0 = MFMA32(vfr[kc], pf[kc], of0);
      of1 = MFMA32(vfr[4 + kc], pf[kc], of1);
    }
    __builtin_amdgcn_s_setprio(0);

    // V(it+2) fragment loads AFTER PV
    {
      const u16* vb = vfb + (size_t)(it + 2) * 4096;
#pragma unroll
      for (int kc = 0; kc < 4; ++kc) {
        vfr[kc] = *(const bf16x8*)(vb + (size_t)kc * 512);
        vfr[4 + kc] = *(const bf16x8*)(vb + (size_t)(4 + kc) * 512);
      }
    }

    // l-sum (off the critical path)
    float t8[8];
#pragma unroll
    for (int i = 0; i < 8; ++i)
      t8[i] = (s0[i] + s0[i + 8]) + (s1[i] + s1[i + 8]);
    float t4a = t8[0] + t8[4], t4b = t8[1] + t8[5];
    float t4c = t8[2] + t8[6], t4d = t8[3] + t8[7];
    l_run += (t4a + t4b) + (t4c + t4d);
  }

  // ---- merge the two KV-halves: fixed reference -> plain ADD ----
  __syncthreads();
  if (half == 1) {
    float* mb = mbuf + (size_t)wsub * 33 * 64 + lane;
#pragma unroll
    for (int i = 0; i < 16; ++i) mb[i * 64] = of0[i];
#pragma unroll
    for (int i = 0; i < 16; ++i) mb[(16 + i) * 64] = of1[i];
    mb[32 * 64] = l_run;
  }
  __syncthreads();
  if (half == 0) {
    const float* mb = mbuf + (size_t)wsub * 33 * 64 + lane;
#pragma unroll
    for (int i = 0; i < 16; ++i) of0[i] += mb[i * 64];
#pragma unroll
    for (int i = 0; i < 16; ++i) of1[i] += mb[(16 + i) * 64];
    l_run += mb[32 * 64];
    float l_tot = l_run + __shfl_xor(l_run, 32);
    float inv_l = 1.0f / l_tot;
    int bb = bh >> 2, hh = bh & 3;
    // fragment-major O store: o_f[b][q32][ck 0..15][lane][8]
    u16* obase = o_f + (size_t)bb * HW * CC;
    int q32 = q0w >> 5;
#pragma unroll
    for (int cb = 0; cb < 2; ++cb) {
      const f32x16 o = cb ? of1 : of0;
#pragma unroll
      for (int oct = 0; oct < 2; ++oct) {
        int ck = hh * 4 + cb * 2 + oct;
        uint4 v = pack_oct(o, oct, inv_l);
        *(uint4*)(obase + ((size_t)(q32 * 16 + ck) * 64 + lane) * 8) = v;
      }
    }
  }
}

// ---------------- Kernel 6: proj GEMM + bias + residual (fp32 out) ----------------
__global__ __launch_bounds__(256) void proj_kernel(const u16* __restrict__ o_f,
                                                   const u16* __restrict__ w_f,
                                                   const float* __restrict__ pb,
                                                   const float* __restrict__ x,
                                                   float* __restrict__ out) {
  int b = blockIdx.z;
  int lane = threadIdx.x & 63, wave = threadIdx.x >> 6;
  int ql = lane & 31, hi = lane >> 5;
  int s0w = blockIdx.x * 128 + (wave >> 1) * 64;
  int o0w = blockIdx.y * 128 + (wave & 1) * 64;   // 0..255
  const u16* ob = o_f + (size_t)b * HW * CC;

  f32x16 acc[2][2];
#pragma unroll
  for (int mo = 0; mo < 2; ++mo)
#pragma unroll
    for (int r = 0; r < 16; ++r) {
      int row = (r & 3) + 8 * (r >> 2) + 4 * hi;
      float bv = pb[o0w + mo * 32 + row];
      acc[mo][0][r] = bv;
      acc[mo][1][r] = bv;
    }

  int os32 = 24 + (o0w >> 5), ss32 = s0w >> 5;
  const u16* wp = w_f + ((size_t)(os32 * 16) * 64 + lane) * 8;
  const u16* op2 = ob + ((size_t)(ss32 * 16) * 64 + lane) * 8;
  bf16x8 af[2], bf2[2], an[2], bn[2];
  af[0] = *(const bf16x8*)(wp);
  af[1] = *(const bf16x8*)(wp + 16 * 512);
  bf2[0] = *(const bf16x8*)(op2);
  bf2[1] = *(const bf16x8*)(op2 + 16 * 512);
#pragma unroll 1
  for (int kk = 0; kk < 16; ++kk) {
    if (kk < 15) {
      an[0] = *(const bf16x8*)(wp + (size_t)(kk + 1) * 512);
      an[1] = *(const bf16x8*)(wp + (size_t)(16 + kk + 1) * 512);
      bn[0] = *(const bf16x8*)(op2 + (size_t)(kk + 1) * 512);
      bn[1] = *(const bf16x8*)(op2 + (size_t)(16 + kk + 1) * 512);
    }
    acc[0][0] = MFMA32(af[0], bf2[0], acc[0][0]);
    acc[0][1] = MFMA32(af[0], bf2[1], acc[0][1]);
    acc[1][0] = MFMA32(af[1], bf2[0], acc[1][0]);
    acc[1][1] = MFMA32(af[1], bf2[1], acc[1][1]);
    af[0] = an[0]; af[1] = an[1]; bf2[0] = bn[0]; bf2[1] = bn[1];
  }

#pragma unroll
  for (int mo = 0; mo < 2; ++mo)
#pragma unroll
    for (int r = 0; r < 16; ++r) {
      int o = o0w + mo * 32 + (r & 3) + 8 * (r >> 2) + 4 * hi;
      const float* xp = x + ((size_t)b * CC + o) * HW + s0w + ql;
      float* op = out + ((size_t)b * CC + o) * HW + s0w + ql;
      op[0] = acc[mo][0][r] + xp[0];
      op[32] = acc[mo][1][r] + xp[32];
    }
}

extern "C" void kernel_launch(void* const* d_in, const int* in_sizes, int n_in,
                              void* d_out, int out_size, void* d_ws, size_t ws_size,
                              hipStream_t stream) {
  const float* x = (const float*)d_in[0];
  const float* nw = (const float*)d_in[1];
  const float* nb = (const float*)d_in[2];
  const float* qw = (const float*)d_in[3];
  const float* qb = (const float*)d_in[4];
  const float* pw = (const float*)d_in[5];
  const float* pb = (const float*)d_in[6];
  float* out = (float*)d_out;

  // workspace layout (o_f aliases h_f: h_f dead after qkv)
  float* stats = (float*)d_ws;                       // 64 floats
  float* partial = stats + 64;                       // 512 floats
  u16* h_f = (u16*)((char*)d_ws + 4096);             // fragment-major  8 MB
  u16* q_f = h_f + (size_t)BB * HW * CC;             // fragment-major  8 MB
  u16* k_f = q_f + (size_t)BB * HW * CC;             // fragment-major  8 MB
  u16* v_f = k_f + (size_t)BB * HW * CC;             // fragment-major  8 MB
  u16* w_f = v_f + (size_t)BB * HW * CC;             // 1024*256 frag   512 KB
  u16* o_f = h_f;                                    // reuse

  gn_partial_kernel<<<256, 256, 0, stream>>>(x, partial);
  gn_final_kernel<<<1, 64, 0, stream>>>(partial, stats);
  w2bf_kernel<<<128, 256, 0, stream>>>(qw, pw, w_f);
  norm_t_kernel<<<dim3(HW / 64, BB), 256, 0, stream>>>(x, nw, nb, stats, h_f);
  qkv_kernel<<<dim3(HW / 128, BB), 256, 0, stream>>>(h_f, w_f, qb, q_f, k_f, v_f);
  attn_kernel<<<dim3(HW / 128, BB * NH), 512, 0, stream>>>(q_f, k_f, v_f, o_f);
  proj_kernel<<<dim3(HW / 128, 2, BB), 256, 0, stream>>>(o_f, w_f, pb, x, out);
}

// Round 20
// 137.826 us; speedup vs baseline: 1.2313x; 1.2313x over previous
//
#include <hip/hip_runtime.h>

typedef unsigned short u16;
typedef __attribute__((ext_vector_type(8))) short bf16x8;
typedef __attribute__((ext_vector_type(16))) float f32x16;
typedef __attribute__((ext_vector_type(2))) int i32x2;

#define MFMA32(A, B, C) __builtin_amdgcn_mfma_f32_32x32x16_bf16((A), (B), (C), 0, 0, 0)

// constants
#define BB 4
#define CC 256
#define HW 4096
#define NH 4
#define HD 64

// 0.125 (d^-0.5) * log2(e): softmax done in exp2 domain
#define QSCALE 0.18033688f

__device__ __forceinline__ u16 f2bf(float f) {
  unsigned int u = __builtin_bit_cast(unsigned int, f);
  u += 0x7fffu + ((u >> 16) & 1u);   // RNE
  return (u16)(u >> 16);
}

__device__ __forceinline__ unsigned cvtpk(float a, float b) {
  unsigned r;
  asm("v_cvt_pk_bf16_f32 %0, %1, %2" : "=v"(r) : "v"(a), "v"(b));
  return r;
}

// D-layout (32x32) octet -> fragment pack: returns lane chunk of 8 bf16 =
// rows oct*16 + hi*8 + 0..7 of this lane's column. scl may be per-lane.
__device__ __forceinline__ uint4 pack_oct(const f32x16& a, int oct, float scl) {
  const int b8 = oct * 8;
  unsigned A0 = cvtpk(a[b8 + 0] * scl, a[b8 + 1] * scl);
  unsigned A1 = cvtpk(a[b8 + 2] * scl, a[b8 + 3] * scl);
  unsigned B0 = cvtpk(a[b8 + 4] * scl, a[b8 + 5] * scl);
  unsigned B1 = cvtpk(a[b8 + 6] * scl, a[b8 + 7] * scl);
  i32x2 r0 = __builtin_amdgcn_permlane32_swap((int)A0, (int)B0, false, false);
  i32x2 r1 = __builtin_amdgcn_permlane32_swap((int)A1, (int)B1, false, false);
  union { unsigned w[4]; uint4 v; } u;
  u.w[0] = (unsigned)r0[0]; u.w[1] = (unsigned)r1[0];
  u.w[2] = (unsigned)r0[1]; u.w[3] = (unsigned)r1[1];
  return u.v;
}

// ---------------- Kernel 0: weights -> FRAGMENT-MAJOR bf16 (once) ----------------
__global__ __launch_bounds__(256) void w2bf_kernel(const float* __restrict__ qw,
                                                   const float* __restrict__ pw,
                                                   u16* __restrict__ w_f) {
  int wv = (blockIdx.x * 256 + threadIdx.x) >> 6;   // 0..511 wave-task
  int lane = threadIdx.x & 63;
  int row = (wv >> 4) * 32 + (lane & 31);
  int c0 = (wv & 15) * 16 + (lane >> 5) * 8;
  const float* src = (row < 768) ? (qw + (size_t)row * 256 + c0)
                                 : (pw + (size_t)(row - 768) * 256 + c0);
  float4 a = *(const float4*)src;
  float4 b = *(const float4*)(src + 4);
  union { u16 u[8]; uint4 v; } pk;
  pk.u[0] = f2bf(a.x); pk.u[1] = f2bf(a.y); pk.u[2] = f2bf(a.z); pk.u[3] = f2bf(a.w);
  pk.u[4] = f2bf(b.x); pk.u[5] = f2bf(b.y); pk.u[6] = f2bf(b.z); pk.u[7] = f2bf(b.w);
  *(uint4*)(w_f + ((size_t)wv * 64 + lane) * 8) = pk.v;
}

// ---------------- Kernel 1a: GroupNorm partial sums (256 blocks) ----------------
__global__ __launch_bounds__(256) void gn_partial_kernel(const float* __restrict__ x,
                                                         float* __restrict__ partial) {
  const float4* p = (const float4*)(x + (size_t)blockIdx.x * 16384);
  float s = 0.f, ss = 0.f;
  for (int i = threadIdx.x; i < 4096; i += 256) {
    float4 v = p[i];
    s += (v.x + v.y) + (v.z + v.w);
    ss += (v.x * v.x + v.y * v.y) + (v.z * v.z + v.w * v.w);
  }
#pragma unroll
  for (int msk = 32; msk; msk >>= 1) {
    s += __shfl_xor(s, msk);
    ss += __shfl_xor(ss, msk);
  }
  __shared__ float red[2][4];
  int wave = threadIdx.x >> 6;
  if ((threadIdx.x & 63) == 0) { red[0][wave] = s; red[1][wave] = ss; }
  __syncthreads();
  if (threadIdx.x == 0) {
    partial[blockIdx.x] = red[0][0] + red[0][1] + red[0][2] + red[0][3];
    partial[256 + blockIdx.x] = red[1][0] + red[1][1] + red[1][2] + red[1][3];
  }
}

// ---------------- Kernel 1b: finalize stats (1 block) ----------------
__global__ __launch_bounds__(64) void gn_final_kernel(const float* __restrict__ partial,
                                                      float* __restrict__ stats) {
  int bg = threadIdx.x;
  if (bg < 32) {
    float S = 0.f, SS = 0.f;
#pragma unroll
    for (int sp = 0; sp < 8; ++sp) {
      S += partial[bg * 8 + sp];
      SS += partial[256 + bg * 8 + sp];
    }
    const float invN = 1.0f / 131072.0f;
    float mean = S * invN;
    float var = SS * invN - mean * mean;
    stats[bg] = mean;
    stats[32 + bg] = rsqrtf(var + 1e-5f);
  }
}

// ---------------- Kernel 2: normalize + LDS-transpose -> h_f FRAGMENT-MAJOR ----------------
// Phase 1 vectorized: each wave-instr reads 4 rows x 16 float4 = 1KB coalesced.
__global__ __launch_bounds__(256) void norm_t_kernel(const float* __restrict__ x,
                                                     const float* __restrict__ nw,
                                                     const float* __restrict__ nb,
                                                     const float* __restrict__ stats,
                                                     u16* __restrict__ h_f) {
  __shared__ u16 L[256][66];   // [c][s] + pad, 33792 B
  int b = blockIdx.y;
  int s0 = blockIdx.x * 64;
  int lane = threadIdx.x & 63, w = threadIdx.x >> 6;
  int c_off = lane >> 4;             // 0..3
  int s_off = (lane & 15) * 4;       // 0,4,..,60
  const float* xb = x + (size_t)b * CC * HW;
#pragma unroll 4
  for (int cc = 0; cc < 16; ++cc) {
    int c = w * 64 + cc * 4 + c_off;
    int g = c >> 5;
    float mean = stats[b * 8 + g];
    float rstd = stats[32 + b * 8 + g];
    float a = nw[c] * rstd;
    float b2 = nb[c] - mean * a;
    float4 v = *(const float4*)(xb + (size_t)c * HW + s0 + s_off);
    union { u16 u[4]; uint2 q; } pk;
    pk.u[0] = f2bf(v.x * a + b2);
    pk.u[1] = f2bf(v.y * a + b2);
    pk.u[2] = f2bf(v.z * a + b2);
    pk.u[3] = f2bf(v.w * a + b2);
    *(uint2*)&L[c][s_off] = pk.q;
  }
  __syncthreads();
  u16* hb = h_f + (size_t)b * HW * CC;
  int ql = lane & 31, hi = lane >> 5;
  for (int t = w; t < 32; t += 4) {
    int s32t = t >> 4, kc = t & 15;
    int c0 = kc * 16 + hi * 8;
    int s = s32t * 32 + ql;
    union { u16 u[8]; uint4 v; } pk;
#pragma unroll
    for (int j = 0; j < 8; ++j) pk.u[j] = L[c0 + j][s];
    int s32g = (s0 >> 5) + s32t;
    *(uint4*)(hb + ((size_t)(s32g * 16 + kc) * 64 + lane) * 8) = pk.v;
  }
}

// ---------------- Kernel 3: unified QKV GEMM, fragment-major in AND out ----------------
// Distance-1 register prefetch on operands (R18 best config, 768 blocks).
__global__ __launch_bounds__(256) void qkv_kernel(const u16* __restrict__ h_f,
                                                  const u16* __restrict__ w_f,
                                                  const float* __restrict__ qb,
                                                  u16* __restrict__ q_f,
                                                  u16* __restrict__ k_f,
                                                  u16* __restrict__ v_f) {
  int b = blockIdx.z;
  int y = blockIdx.y;
  int lane = threadIdx.x & 63, wave = threadIdx.x >> 6;
  int ql = lane & 31, hi = lane >> 5;
  int s0w = blockIdx.x * 128 + (wave >> 1) * 64;
  int o0w = y * 128 + (wave & 1) * 64;          // 0..767, multiple of 64
  bool isV = (y >= 4);
  const u16* hb = h_f + (size_t)b * HW * CC;

  f32x16 acc[2][2];
  if (!isV) {
#pragma unroll
    for (int mo = 0; mo < 2; ++mo)
#pragma unroll
      for (int r = 0; r < 16; ++r) {
        int row = (r & 3) + 8 * (r >> 2) + 4 * hi;
        float bv = qb[o0w + mo * 32 + row];
        acc[mo][0][r] = bv;
        acc[mo][1][r] = bv;
      }
  } else {
#pragma unroll
    for (int ns = 0; ns < 2; ++ns) {
      float bv = qb[o0w + ns * 32 + ql];
#pragma unroll
      for (int r = 0; r < 16; ++r) {
        acc[0][ns][r] = bv;
        acc[1][ns][r] = bv;
      }
    }
  }

  int os32 = o0w >> 5, ss32 = s0w >> 5;
  const u16* wp = w_f + ((size_t)(os32 * 16) * 64 + lane) * 8;
  const u16* hp = hb + ((size_t)(ss32 * 16) * 64 + lane) * 8;
  bf16x8 wf[2], hf[2], wn[2], hn[2];
  wf[0] = *(const bf16x8*)(wp);
  wf[1] = *(const bf16x8*)(wp + 16 * 512);
  hf[0] = *(const bf16x8*)(hp);
  hf[1] = *(const bf16x8*)(hp + 16 * 512);
#pragma unroll 1
  for (int kk = 0; kk < 16; ++kk) {
    if (kk < 15) {
      wn[0] = *(const bf16x8*)(wp + (size_t)(kk + 1) * 512);
      wn[1] = *(const bf16x8*)(wp + (size_t)(16 + kk + 1) * 512);
      hn[0] = *(const bf16x8*)(hp + (size_t)(kk + 1) * 512);
      hn[1] = *(const bf16x8*)(hp + (size_t)(16 + kk + 1) * 512);
    }
    if (!isV) {
      acc[0][0] = MFMA32(wf[0], hf[0], acc[0][0]);
      acc[0][1] = MFMA32(wf[0], hf[1], acc[0][1]);
      acc[1][0] = MFMA32(wf[1], hf[0], acc[1][0]);
      acc[1][1] = MFMA32(wf[1], hf[1], acc[1][1]);
    } else {
      acc[0][0] = MFMA32(hf[0], wf[0], acc[0][0]);
      acc[0][1] = MFMA32(hf[0], wf[1], acc[0][1]);
      acc[1][0] = MFMA32(hf[1], wf[0], acc[1][0]);
      acc[1][1] = MFMA32(hf[1], wf[1], acc[1][1]);
    }
    wf[0] = wn[0]; wf[1] = wn[1]; hf[0] = hn[0]; hf[1] = hn[1];
  }

  if (!isV) {
    bool isQ = (y < 2);
    float scl = isQ ? QSCALE : 1.0f;
    int headL = (o0w >> 6) - (isQ ? 0 : 4);
    u16* base = (isQ ? q_f : k_f) + (size_t)(b * NH + headL) * HW * HD;
#pragma unroll
    for (int mo = 0; mo < 2; ++mo)
#pragma unroll
      for (int ns = 0; ns < 2; ++ns) {
        int s32 = ss32 + ns;
#pragma unroll
        for (int oct = 0; oct < 2; ++oct) {
          int kc = mo * 2 + oct;
          uint4 v = pack_oct(acc[mo][ns], oct, scl);
          *(uint4*)(base + ((size_t)(s32 * 4 + kc) * 64 + lane) * 8) = v;
        }
      }
  } else {
    int headv = (o0w >> 6) - 8;
    u16* base = v_f + (size_t)(b * NH + headv) * HW * HD;
#pragma unroll
    for (int mo = 0; mo < 2; ++mo)
#pragma unroll
      for (int ns = 0; ns < 2; ++ns)
#pragma unroll
        for (int oct = 0; oct < 2; ++oct) {
          int kvb = s0w + mo * 32 + oct * 16;
          int jb64 = kvb >> 6, kcv = (kvb & 63) >> 4;
          uint4 v = pack_oct(acc[mo][ns], oct, 1.0f);
          *(uint4*)(base + ((size_t)((jb64 * 2 + ns) * 4 + kcv) * 64 + lane) * 8) = v;
        }
  }
}

// ---------------- Kernel 5: flash attention, LDS-free + split-KV x2 (best) ----------------
__global__ __launch_bounds__(512) void attn_kernel(const u16* __restrict__ q_f,
                                                   const u16* __restrict__ k_f,
                                                   const u16* __restrict__ v_f,
                                                   u16* __restrict__ o_f) {
  __shared__ float mbuf[4 * 33 * 64];   // [wsub][of0(16)|of1(16)|l(1)][lane]
  int wgid = blockIdx.x + gridDim.x * blockIdx.y;
  int xcd = wgid & 7;
  int j = wgid >> 3;
  int bh = (xcd << 1) | (j & 1);       // each XCD owns 2 bh -> L2-resident K/V
  int qblk = j >> 1;
  int tid = threadIdx.x;
  int wave = tid >> 6, lane = tid & 63;
  int half = wave >> 2, wsub = wave & 3;
  int ql = lane & 31, hi = lane >> 5;
  int q0w = qblk * 128 + wsub * 32;
  const u16* qfb = q_f + (size_t)bh * HW * HD + lane * 8;
  const u16* kfb = k_f + (size_t)bh * HW * HD + lane * 8;
  const u16* vfb = v_f + (size_t)bh * HW * HD + lane * 8;

  // Q B-fragments from fragment-major layout
  int s32q = q0w >> 5;
  bf16x8 qf[4];
#pragma unroll
  for (int kc = 0; kc < 4; ++kc)
    qf[kc] = *(const bf16x8*)(qfb + (size_t)(s32q * 4 + kc) * 512);

  float l_run = 0.f;
  f32x16 of0 = {}, of1 = {};
  bf16x8 kfr[8], vfr[8];

  // prologue: K(half), V(half) fragments
  {
    const u16* kb = kfb + (size_t)half * 4096;
    const u16* vb = vfb + (size_t)half * 4096;
#pragma unroll
    for (int kc = 0; kc < 4; ++kc) {
      kfr[kc] = *(const bf16x8*)(kb + (size_t)kc * 512);
      kfr[4 + kc] = *(const bf16x8*)(kb + (size_t)(4 + kc) * 512);
      vfr[kc] = *(const bf16x8*)(vb + (size_t)kc * 512);
      vfr[4 + kc] = *(const bf16x8*)(vb + (size_t)(4 + kc) * 512);
    }
  }

#pragma unroll 1
  for (int it = half; it < 64; it += 2) {
    // QK(it): S[kv][q] = K·Q  (scale+log2e folded into q)
    f32x16 s0 = {}, s1 = {};
    __builtin_amdgcn_s_setprio(1);
#pragma unroll
    for (int kc = 0; kc < 4; ++kc) {
      s0 = MFMA32(kfr[kc], qf[kc], s0);
      s1 = MFMA32(kfr[4 + kc], qf[kc], s1);
    }
    __builtin_amdgcn_s_setprio(0);

    // K(it+2) fragment loads (consumed next iteration)
    {
      const u16* kb = kfb + (size_t)(it + 2) * 4096;
#pragma unroll
      for (int kc = 0; kc < 4; ++kc) {
        kfr[kc] = *(const bf16x8*)(kb + (size_t)kc * 512);
        kfr[4 + kc] = *(const bf16x8*)(kb + (size_t)(4 + kc) * 512);
      }
    }

    // P = exp2(S) directly — fixed reference (no max tracking)
#pragma unroll
    for (int i = 0; i < 16; ++i) {
      s0[i] = __builtin_amdgcn_exp2f(s0[i]);
      s1[i] = __builtin_amdgcn_exp2f(s1[i]);
    }

    // pf(it) = P -> bf16 B-fragments via cvt_pk + permlane32_swap
    bf16x8 pf[4];
#pragma unroll
    for (int kc = 0; kc < 4; ++kc) {
      const f32x16 pv = (kc < 2) ? s0 : s1;
      const int b8 = (kc & 1) * 8;
      unsigned A0 = cvtpk(pv[b8 + 0], pv[b8 + 1]);
      unsigned A1 = cvtpk(pv[b8 + 2], pv[b8 + 3]);
      unsigned B0 = cvtpk(pv[b8 + 4], pv[b8 + 5]);
      unsigned B1 = cvtpk(pv[b8 + 6], pv[b8 + 7]);
      i32x2 r0 = __builtin_amdgcn_permlane32_swap((int)A0, (int)B0, false, false);
      i32x2 r1 = __builtin_amdgcn_permlane32_swap((int)A1, (int)B1, false, false);
      union { unsigned w[4]; bf16x8 v8; } u;
      u.w[0] = (unsigned)r0[0]; u.w[1] = (unsigned)r1[0];
      u.w[2] = (unsigned)r0[1]; u.w[3] = (unsigned)r1[1];
      pf[kc] = u.v8;
    }

    // PV(it): O^T[c][q] += V^T · P^T
    __builtin_amdgcn_s_setprio(1);
#pragma unroll
    for (int kc = 0; kc < 4; ++kc) {
      of0 = MFMA32(vfr[kc], pf[kc], of0);
      of1 = MFMA32(vfr[4 + kc], pf[kc], of1);
    }
    __builtin_amdgcn_s_setprio(0);

    // V(it+2) fragment loads AFTER PV
    {
      const u16* vb = vfb + (size_t)(it + 2) * 4096;
#pragma unroll
      for (int kc = 0; kc < 4; ++kc) {
        vfr[kc] = *(const bf16x8*)(vb + (size_t)kc * 512);
        vfr[4 + kc] = *(const bf16x8*)(vb + (size_t)(4 + kc) * 512);
      }
    }

    // l-sum (off the critical path)
    float t8[8];
#pragma unroll
    for (int i = 0; i < 8; ++i)
      t8[i] = (s0[i] + s0[i + 8]) + (s1[i] + s1[i + 8]);
    float t4a = t8[0] + t8[4], t4b = t8[1] + t8[5];
    float t4c = t8[2] + t8[6], t4d = t8[3] + t8[7];
    l_run += (t4a + t4b) + (t4c + t4d);
  }

  // ---- merge the two KV-halves: fixed reference -> plain ADD ----
  __syncthreads();
  if (half == 1) {
    float* mb = mbuf + (size_t)wsub * 33 * 64 + lane;
#pragma unroll
    for (int i = 0; i < 16; ++i) mb[i * 64] = of0[i];
#pragma unroll
    for (int i = 0; i < 16; ++i) mb[(16 + i) * 64] = of1[i];
    mb[32 * 64] = l_run;
  }
  __syncthreads();
  if (half == 0) {
    const float* mb = mbuf + (size_t)wsub * 33 * 64 + lane;
#pragma unroll
    for (int i = 0; i < 16; ++i) of0[i] += mb[i * 64];
#pragma unroll
    for (int i = 0; i < 16; ++i) of1[i] += mb[(16 + i) * 64];
    l_run += mb[32 * 64];
    float l_tot = l_run + __shfl_xor(l_run, 32);
    float inv_l = 1.0f / l_tot;
    int bb = bh >> 2, hh = bh & 3;
    // fragment-major O store: o_f[b][q32][ck 0..15][lane][8]
    u16* obase = o_f + (size_t)bb * HW * CC;
    int q32 = q0w >> 5;
#pragma unroll
    for (int cb = 0; cb < 2; ++cb) {
      const f32x16 o = cb ? of1 : of0;
#pragma unroll
      for (int oct = 0; oct < 2; ++oct) {
        int ck = hh * 4 + cb * 2 + oct;
        uint4 v = pack_oct(o, oct, inv_l);
        *(uint4*)(obase + ((size_t)(q32 * 16 + ck) * 64 + lane) * 8) = v;
      }
    }
  }
}

// ---------------- Kernel 6: proj GEMM + bias + residual (fp32 out) ----------------
// Distance-1 register prefetch on operands (same as qkv).
__global__ __launch_bounds__(256) void proj_kernel(const u16* __restrict__ o_f,
                                                   const u16* __restrict__ w_f,
                                                   const float* __restrict__ pb,
                                                   const float* __restrict__ x,
                                                   float* __restrict__ out) {
  int b = blockIdx.z;
  int lane = threadIdx.x & 63, wave = threadIdx.x >> 6;
  int ql = lane & 31, hi = lane >> 5;
  int s0w = blockIdx.x * 128 + (wave >> 1) * 64;
  int o0w = blockIdx.y * 128 + (wave & 1) * 64;   // 0..255
  const u16* ob = o_f + (size_t)b * HW * CC;

  f32x16 acc[2][2];
#pragma unroll
  for (int mo = 0; mo < 2; ++mo)
#pragma unroll
    for (int r = 0; r < 16; ++r) {
      int row = (r & 3) + 8 * (r >> 2) + 4 * hi;
      float bv = pb[o0w + mo * 32 + row];
      acc[mo][0][r] = bv;
      acc[mo][1][r] = bv;
    }

  int os32 = 24 + (o0w >> 5), ss32 = s0w >> 5;
  const u16* wp = w_f + ((size_t)(os32 * 16) * 64 + lane) * 8;
  const u16* op2 = ob + ((size_t)(ss32 * 16) * 64 + lane) * 8;
  bf16x8 af[2], bf2[2], an[2], bn[2];
  af[0] = *(const bf16x8*)(wp);
  af[1] = *(const bf16x8*)(wp + 16 * 512);
  bf2[0] = *(const bf16x8*)(op2);
  bf2[1] = *(const bf16x8*)(op2 + 16 * 512);
#pragma unroll 1
  for (int kk = 0; kk < 16; ++kk) {
    if (kk < 15) {
      an[0] = *(const bf16x8*)(wp + (size_t)(kk + 1) * 512);
      an[1] = *(const bf16x8*)(wp + (size_t)(16 + kk + 1) * 512);
      bn[0] = *(const bf16x8*)(op2 + (size_t)(kk + 1) * 512);
      bn[1] = *(const bf16x8*)(op2 + (size_t)(16 + kk + 1) * 512);
    }
    acc[0][0] = MFMA32(af[0], bf2[0], acc[0][0]);
    acc[0][1] = MFMA32(af[0], bf2[1], acc[0][1]);
    acc[1][0] = MFMA32(af[1], bf2[0], acc[1][0]);
    acc[1][1] = MFMA32(af[1], bf2[1], acc[1][1]);
    af[0] = an[0]; af[1] = an[1]; bf2[0] = bn[0]; bf2[1] = bn[1];
  }

#pragma unroll
  for (int mo = 0; mo < 2; ++mo)
#pragma unroll
    for (int r = 0; r < 16; ++r) {
      int o = o0w + mo * 32 + (r & 3) + 8 * (r >> 2) + 4 * hi;
      const float* xp = x + ((size_t)b * CC + o) * HW + s0w + ql;
      float* op = out + ((size_t)b * CC + o) * HW + s0w + ql;
      op[0] = acc[mo][0][r] + xp[0];
      op[32] = acc[mo][1][r] + xp[32];
    }
}

extern "C" void kernel_launch(void* const* d_in, const int* in_sizes, int n_in,
                              void* d_out, int out_size, void* d_ws, size_t ws_size,
                              hipStream_t stream) {
  const float* x = (const float*)d_in[0];
  const float* nw = (const float*)d_in[1];
  const float* nb = (const float*)d_in[2];
  const float* qw = (const float*)d_in[3];
  const float* qb = (const float*)d_in[4];
  const float* pw = (const float*)d_in[5];
  const float* pb = (const float*)d_in[6];
  float* out = (float*)d_out;

  // workspace layout (o_f aliases h_f: h_f dead after qkv)
  float* stats = (float*)d_ws;                       // 64 floats
  float* partial = stats + 64;                       // 512 floats
  u16* h_f = (u16*)((char*)d_ws + 4096);             // fragment-major  8 MB
  u16* q_f = h_f + (size_t)BB * HW * CC;             // fragment-major  8 MB
  u16* k_f = q_f + (size_t)BB * HW * CC;             // fragment-major  8 MB
  u16* v_f = k_f + (size_t)BB * HW * CC;             // fragment-major  8 MB
  u16* w_f = v_f + (size_t)BB * HW * CC;             // 1024*256 frag   512 KB
  u16* o_f = h_f;                                    // reuse

  gn_partial_kernel<<<256, 256, 0, stream>>>(x, partial);
  gn_final_kernel<<<1, 64, 0, stream>>>(partial, stats);
  w2bf_kernel<<<128, 256, 0, stream>>>(qw, pw, w_f);
  norm_t_kernel<<<dim3(HW / 64, BB), 256, 0, stream>>>(x, nw, nb, stats, h_f);
  qkv_kernel<<<dim3(HW / 128, 6, BB), 256, 0, stream>>>(h_f, w_f, qb, q_f, k_f, v_f);
  attn_kernel<<<dim3(HW / 128, BB * NH), 512, 0, stream>>>(q_f, k_f, v_f, o_f);
  proj_kernel<<<dim3(HW / 128, 2, BB), 256, 0, stream>>>(o_f, w_f, pb, x, out);
}